// Round 15
// baseline (129.344 us; speedup 1.0000x reference)
//
#include <hip/hip_runtime.h>

#define N_REAL 12
#define BATCH  4
#define CH     3
#define HH     256
#define WW     256
#define KK     4
#define TY     8                  // output rows per block (4 waves x 2 rows)
#define NTHR   256
#define HW     (HH * WW)
#define WROWS  5                  // rows each wave stages (2 out + 3 halo)
#define RSTR   264                // row stride (dwords): 256 data + 8 zero pad
#define WBUF   (4 + WROWS * RSTR) // guard quad + rows = 1324 dw = 5296 B

typedef float f32x4 __attribute__((ext_vector_type(4)));

__device__ __forceinline__ float sigmoidf(float x) {
    float e = __builtin_amdgcn_exp2f(x * -1.44269504088896340736f);
    return __builtin_amdgcn_rcpf(1.0f + e);
}

// compiler-only fence: DS pipe is in-order per wave, so forbidding compiler
// reordering of LDS ops is sufficient for wave-synchronous write->read.
#define LDS_FENCE() asm volatile("" ::: "memory")

__global__ __launch_bounds__(NTHR, 4)
void reverb_fused(const float* __restrict__ states,
                  const float* __restrict__ weights,
                  const float* __restrict__ bias,
                  float*       __restrict__ out)
{
    // wave-private buffers: NO __syncthreads in this kernel
    __shared__ __align__(16) float S[4][WBUF];   // 21.2 KB -> 6 blocks/CU

    const int ty  = blockIdx.x;            // 0..31
    const int b   = blockIdx.y;            // batch
    const int v   = blockIdx.z;            // dest node
    const int tid = threadIdx.x;
    const int w   = tid >> 6;              // wave: owns output rows gy0+2w, 2w+1
    const int ln  = tid & 63;              // lane: owns cols 4ln..4ln+3
    const int gy0 = ty * TY;
    const int deg = (v == 0) ? 4 : 3;
    float* const myS = &S[w][0];

    // ---- one-time zero of this wave's guard + row pads (44 dwords) ----
    if (ln < 4 + WROWS * 8) {
        if (ln < 4) myS[ln] = 0.0f;
        else {
            const int i = ln - 4;
            myS[4 + (i >> 3) * RSTR + 256 + (i & 7)] = 0.0f;
        }
    }
    LDS_FENCE();

    // ---- per-row gather metadata: rows gy0+2w-1+k ----
    int  goffs[WROWS];
    bool rowok[WROWS];
    #pragma unroll
    for (int k = 0; k < WROWS; ++k) {
        const int gy  = gy0 + 2 * w - 1 + k;
        const int gyc = gy < 0 ? 0 : (gy > HH - 1 ? HH - 1 : gy);
        goffs[k] = gyc * WW + 4 * ln;
        rowok[k] = (unsigned)gy < (unsigned)HH;   // wave-uniform
    }

    // ---- edge tables (uniform) ----
    int ucA[4], eA[4];
    #pragma unroll
    for (int ei = 0; ei < 4; ++ei) {
        int t = v + 11 - ei; if (t >= 12) t -= 12;
        ucA[ei] = (ei == 3) ? 12 : t;
        eA[ei]  = (ei == 3) ? 36 : (ucA[ei] * 3 + ei);
    }

    float bsum[CH] = {0.f, 0.f, 0.f};
    for (int ei = 0; ei < deg; ++ei) {
        bsum[0] += bias[eA[ei] * CH + 0];
        bsum[1] += bias[eA[ei] * CH + 1];
        bsum[2] += bias[eA[ei] * CH + 2];
    }

    float acc[CH][2][4];
    #pragma unroll
    for (int co = 0; co < CH; ++co)
        #pragma unroll
        for (int yy = 0; yy < 2; ++yy)
            #pragma unroll
            for (int p = 0; p < 4; ++p) acc[co][yy][p] = 0.0f;

    for (int ei = 0; ei < deg; ++ei) {
        const float* __restrict__ srcE  =
            states + (size_t)(ucA[ei] * BATCH + b) * CH * HW;
        const float* __restrict__ wbase = weights + eA[ei] * (CH * CH * KK * KK);

        #pragma unroll
        for (int ci = 0; ci < CH; ++ci) {
            const float* __restrict__ srcC = srcE + (size_t)ci * HW;

            // ---- load 5 rows (coalesced), sigmoid, keep in regs ----
            f32x4 s[WROWS];
            #pragma unroll
            for (int k = 0; k < WROWS; ++k) {
                const f32x4 q = *(const f32x4*)(srcC + goffs[k]);
                if (rowok[k]) {
                    s[k].x = sigmoidf(q.x); s[k].y = sigmoidf(q.y);
                    s[k].z = sigmoidf(q.z); s[k].w = sigmoidf(q.w);
                } else {
                    s[k] = (f32x4){0.f, 0.f, 0.f, 0.f};
                }
            }
            // ---- publish to wave-private LDS ----
            #pragma unroll
            for (int k = 0; k < WROWS; ++k)
                *(f32x4*)(myS + 4 + k * RSTR + 4 * ln) = s[k];
            LDS_FENCE();                   // writes stay above the halo reads

            // ---- compute: halo quads from LDS, middle from regs ----
            #pragma unroll
            for (int lr = 0; lr < WROWS; ++lr) {
                const float* rp = myS + 4 + lr * RSTR + 4 * ln;
                const f32x4 A = *(const f32x4*)(rp - 4);   // A.w = x-1
                const f32x4 C = *(const f32x4*)(rp + 4);   // C.x,C.y = x+4,x+5
                const float vv[7] = {A.w, s[lr].x, s[lr].y, s[lr].z, s[lr].w,
                                     C.x, C.y};
                #pragma unroll
                for (int yy = 0; yy < 2; ++yy) {
                    const int ky = lr - yy;
                    if (ky < 0 || ky > 3) continue;
                    #pragma unroll
                    for (int co = 0; co < CH; ++co) {
                        const f32x4 wv =
                            *(const f32x4*)(wbase + ((co * CH + ci) * KK + ky) * KK);
                        #pragma unroll
                        for (int p = 0; p < 4; ++p) {
                            acc[co][yy][p] = fmaf(wv.x, vv[p + 0], acc[co][yy][p]);
                            acc[co][yy][p] = fmaf(wv.y, vv[p + 1], acc[co][yy][p]);
                            acc[co][yy][p] = fmaf(wv.z, vv[p + 2], acc[co][yy][p]);
                            acc[co][yy][p] = fmaf(wv.w, vv[p + 3], acc[co][yy][p]);
                        }
                    }
                }
            }
            LDS_FENCE();                   // reads stay above next phase's writes
        }
    }

    const float inv = 1.0f / (float)deg;
    const size_t obase = (size_t)(v * BATCH + b) * CH * HW;
    #pragma unroll
    for (int co = 0; co < CH; ++co) {
        #pragma unroll
        for (int yy = 0; yy < 2; ++yy) {
            const int oy = gy0 + 2 * w + yy;
            f32x4 o;
            o.x = (acc[co][yy][0] + bsum[co]) * inv;
            o.y = (acc[co][yy][1] + bsum[co]) * inv;
            o.z = (acc[co][yy][2] + bsum[co]) * inv;
            o.w = (acc[co][yy][3] + bsum[co]) * inv;
            __builtin_nontemporal_store(o,
                (f32x4*)&out[obase + (size_t)co * HW + (size_t)oy * WW + 4 * ln]);
        }
    }
}

extern "C" void kernel_launch(void* const* d_in, const int* in_sizes, int n_in,
                              void* d_out, int out_size, void* d_ws, size_t ws_size,
                              hipStream_t stream)
{
    const float* states  = (const float*)d_in[0];
    const float* weights = (const float*)d_in[1];
    const float* bias    = (const float*)d_in[2];
    float*       out     = (float*)d_out;

    dim3 grid(HH / TY, BATCH, N_REAL);     // 32 x 4 x 12 = 1536 blocks
    reverb_fused<<<grid, NTHR, 0, stream>>>(states, weights, bias, out);
}

// Round 16
// 49.037 us; speedup vs baseline: 2.6377x; 2.6377x over previous
//
#include <hip/hip_runtime.h>
#include <stdint.h>

#define N_REAL 12
#define BATCH  4
#define CH     3
#define HH     256
#define WW     256
#define KK     4
#define TY     8                  // output rows per block (4 waves x 2 rows)
#define ROWSR  11                 // TY + KK - 1 input rows
#define RSTR   264                // LDS row stride (dwords): 256 data + 8 zero pad
#define NTHR   256
#define HW     (HH * WW)
#define BUFSZ  (4 + ROWSR * RSTR) // guard quad + rows = 2908 dwords
#define NPAD   (4 + ROWSR * 8)    // guard + per-row pads = 92 dwords per buffer

typedef float f32x4 __attribute__((ext_vector_type(4)));
typedef __attribute__((address_space(1))) const void gas_t;
typedef __attribute__((address_space(3))) void las_t;

// async global->LDS DMA: dest = wave-uniform row base + lane*16 (linear), exactly
// one 256-dword row per issue; raw data, sigmoid applied in-place later.
#define ASYNC_ROW16(gsrc, ldst) \
    __builtin_amdgcn_global_load_lds((gas_t*)(gsrc), (las_t*)(ldst), 16, 0, 0)

__device__ __forceinline__ float sigmoidf(float x) {
    float e = __builtin_amdgcn_exp2f(x * -1.44269504088896340736f);
    return __builtin_amdgcn_rcpf(1.0f + e);
}

__global__ __launch_bounds__(NTHR, 4)
void reverb_fused(const float* __restrict__ states,
                  const float* __restrict__ weights,
                  const float* __restrict__ bias,
                  float*       __restrict__ out)
{
    __shared__ __align__(16) float S[2][BUFSZ];   // 23.3 KB -> 6 blocks/CU

    const int ty  = blockIdx.x;            // 0..31
    const int b   = blockIdx.y;            // batch
    const int v   = blockIdx.z;            // dest node
    const int tid = threadIdx.x;
    const int w   = tid >> 6;              // wave: owns output rows gy0+2w, 2w+1
    const int ln  = tid & 63;              // lane: owns cols 4ln..4ln+3
    const int gy0 = ty * TY;
    const int deg = (v == 0) ? 4 : 3;
    const int P   = 3 * deg;               // (edge,channel) phases

    // ---- one-time zero of guard + row pads in BOTH buffers (disjoint from DMA data) ----
    if (tid < 2 * NPAD) {
        const int bi = (tid >= NPAD) ? 1 : 0;
        const int j  = tid - bi * NPAD;
        if (j < 4) S[bi][j] = 0.0f;
        else {
            const int i = j - 4;
            S[bi][4 + (i >> 3) * RSTR + 256 + (i & 7)] = 0.0f;
        }
    }

    // ---- staging metadata: wave w owns rows w, w+4, w+8 (r < 11) ----
    int  rr[3], goff[3];
    bool rvalid[3], rowok[3];
    #pragma unroll
    for (int k = 0; k < 3; ++k) {
        const int r = w + 4 * k;
        rr[k]     = r;
        rvalid[k] = (r < ROWSR);           // wave-uniform
        const int gy  = gy0 + r - 1;       // SAME pad lo=1
        const int gyc = gy < 0 ? 0 : (gy > HH - 1 ? HH - 1 : gy);
        goff[k]  = gyc * WW + 4 * ln;      // per-lane global dword offset
        rowok[k] = (unsigned)gy < (unsigned)HH;
    }

    // ---- edge tables (uniform) ----
    int ucA[4], eA[4];
    #pragma unroll
    for (int ei = 0; ei < 4; ++ei) {
        int t = v + 11 - ei; if (t >= 12) t -= 12;
        ucA[ei] = (ei == 3) ? 12 : t;
        eA[ei]  = (ei == 3) ? 36 : (ucA[ei] * 3 + ei);
    }

    float bsum[CH] = {0.f, 0.f, 0.f};
    for (int ei = 0; ei < deg; ++ei) {
        bsum[0] += bias[eA[ei] * CH + 0];
        bsum[1] += bias[eA[ei] * CH + 1];
        bsum[2] += bias[eA[ei] * CH + 2];
    }

    float acc[CH][2][4];
    #pragma unroll
    for (int co = 0; co < CH; ++co)
        #pragma unroll
        for (int yy = 0; yy < 2; ++yy)
            #pragma unroll
            for (int p = 0; p < 4; ++p) acc[co][yy][p] = 0.0f;

    // ---- prologue: DMA phase 0 into S[0], wait, sigmoid in place ----
    {
        const float* srcC0 = states + (size_t)(ucA[0] * BATCH + b) * CH * HW; // ci=0
        #pragma unroll
        for (int k = 0; k < 3; ++k)
            if (rvalid[k])
                ASYNC_ROW16(srcC0 + goff[k], &S[0][4 + rr[k] * RSTR]);
        asm volatile("s_waitcnt vmcnt(0)" ::: "memory");
        __builtin_amdgcn_sched_barrier(0);
        #pragma unroll
        for (int k = 0; k < 3; ++k) {
            if (rvalid[k]) {
                float* rp = &S[0][4 + rr[k] * RSTR + 4 * ln];
                const f32x4 q = *(const f32x4*)rp;
                f32x4 t;
                if (rowok[k]) {
                    t.x = sigmoidf(q.x); t.y = sigmoidf(q.y);
                    t.z = sigmoidf(q.z); t.w = sigmoidf(q.w);
                } else t = (f32x4){0.f, 0.f, 0.f, 0.f};
                *(f32x4*)rp = t;
            }
        }
    }
    __syncthreads();

    for (int p = 0; p < P; ++p) {
        const int cur  = p & 1;
        const bool more = (p + 1 < P);

        // ---- issue next phase's DMA into the freed buffer (zero VGPR cost) ----
        if (more) {
            const int p1  = p + 1;
            const int ei1 = p1 / 3;
            const int ci1 = p1 - 3 * ei1;
            const float* srcC1 = states +
                (size_t)(ucA[ei1] * BATCH + b) * CH * HW + (size_t)ci1 * HW;
            #pragma unroll
            for (int k = 0; k < 3; ++k)
                if (rvalid[k])
                    ASYNC_ROW16(srcC1 + goff[k], &S[cur ^ 1][4 + rr[k] * RSTR]);
        }

        // ---- compute phase p from S[cur] (covers the DMA latency) ----
        {
            const int ei = p / 3;
            const int ci = p - 3 * ei;
            const float* __restrict__ wbase = weights + eA[ei] * (CH * CH * KK * KK);
            #pragma unroll
            for (int lr = 0; lr < 5; ++lr) {
                const float* rp = &S[cur][4 + (2 * w + lr) * RSTR + 4 * ln];
                const f32x4 A  = *(const f32x4*)(rp - 4);   // A.w = x-1 (guard/pad)
                const f32x4 Bq = *(const f32x4*)(rp);
                const f32x4 Cq = *(const f32x4*)(rp + 4);   // C.x,C.y = x+4,x+5
                const float vv[7] = {A.w, Bq.x, Bq.y, Bq.z, Bq.w, Cq.x, Cq.y};
                #pragma unroll
                for (int yy = 0; yy < 2; ++yy) {
                    const int ky = lr - yy;
                    if (ky < 0 || ky > 3) continue;
                    #pragma unroll
                    for (int co = 0; co < CH; ++co) {
                        const f32x4 wv =
                            *(const f32x4*)(wbase + ((co * CH + ci) * KK + ky) * KK);
                        #pragma unroll
                        for (int pp = 0; pp < 4; ++pp) {
                            acc[co][yy][pp] = fmaf(wv.x, vv[pp + 0], acc[co][yy][pp]);
                            acc[co][yy][pp] = fmaf(wv.y, vv[pp + 1], acc[co][yy][pp]);
                            acc[co][yy][pp] = fmaf(wv.z, vv[pp + 2], acc[co][yy][pp]);
                            acc[co][yy][pp] = fmaf(wv.w, vv[pp + 3], acc[co][yy][pp]);
                        }
                    }
                }
            }
        }

        // ---- wave-local: wait own DMA, sigmoid next tile in place ----
        if (more) {
            asm volatile("s_waitcnt vmcnt(0)" ::: "memory");
            __builtin_amdgcn_sched_barrier(0);
            #pragma unroll
            for (int k = 0; k < 3; ++k) {
                if (rvalid[k]) {
                    float* rp = &S[cur ^ 1][4 + rr[k] * RSTR + 4 * ln];
                    const f32x4 q = *(const f32x4*)rp;
                    f32x4 t;
                    if (rowok[k]) {
                        t.x = sigmoidf(q.x); t.y = sigmoidf(q.y);
                        t.z = sigmoidf(q.z); t.w = sigmoidf(q.w);
                    } else t = (f32x4){0.f, 0.f, 0.f, 0.f};
                    *(f32x4*)rp = t;
                }
            }
            __syncthreads();               // single barrier per phase
        }
    }

    const float inv = 1.0f / (float)deg;
    const size_t obase = (size_t)(v * BATCH + b) * CH * HW;
    #pragma unroll
    for (int co = 0; co < CH; ++co) {
        #pragma unroll
        for (int yy = 0; yy < 2; ++yy) {
            const int oy = gy0 + 2 * w + yy;
            f32x4 o;
            o.x = (acc[co][yy][0] + bsum[co]) * inv;
            o.y = (acc[co][yy][1] + bsum[co]) * inv;
            o.z = (acc[co][yy][2] + bsum[co]) * inv;
            o.w = (acc[co][yy][3] + bsum[co]) * inv;
            __builtin_nontemporal_store(o,
                (f32x4*)&out[obase + (size_t)co * HW + (size_t)oy * WW + 4 * ln]);
        }
    }
}

extern "C" void kernel_launch(void* const* d_in, const int* in_sizes, int n_in,
                              void* d_out, int out_size, void* d_ws, size_t ws_size,
                              hipStream_t stream)
{
    const float* states  = (const float*)d_in[0];
    const float* weights = (const float*)d_in[1];
    const float* bias    = (const float*)d_in[2];
    float*       out     = (float*)d_out;

    dim3 grid(HH / TY, BATCH, N_REAL);     // 32 x 4 x 12 = 1536 blocks, 6/CU resident
    reverb_fused<<<grid, NTHR, 0, stream>>>(states, weights, bias, out);
}